// Round 1
// 529.056 us; speedup vs baseline: 1.0684x; 1.0684x over previous
//
#include <hip/hip_runtime.h>

#define BB 8
#define MM 4096
#define EE 2048
#define DD 128

typedef _Float16 f16x8 __attribute__((ext_vector_type(8)));
typedef float    f32x4 __attribute__((ext_vector_type(4)));

// ---------------------------------------------------------------------------
// transpose_to16: src [R][C] fp32 -> dst [C][R] f16, batch = blockIdx.y.
// ---------------------------------------------------------------------------
__global__ __launch_bounds__(256) void transpose_to16(const float* __restrict__ src,
                                                      _Float16* __restrict__ dst,
                                                      int R, int C)
{
    __shared__ alignas(16) float tile[64 * 67];
    const int tilesC = C >> 6;
    const int r0 = (blockIdx.x / tilesC) << 6;
    const int c0 = (blockIdx.x % tilesC) << 6;
    const float* s = src + (size_t)blockIdx.y * R * C;
    _Float16*   d = dst + (size_t)blockIdx.y * R * C;
    const int t = threadIdx.x;
    #pragma unroll
    for (int i = 0; i < 4; i++){
        int idx = t + 256 * i;
        int r = idx >> 4, c4 = idx & 15;
        float4 v = *(const float4*)(s + (size_t)(r0 + r) * C + c0 + c4 * 4);
        tile[(c4 * 4 + 0) * 67 + r] = v.x;
        tile[(c4 * 4 + 1) * 67 + r] = v.y;
        tile[(c4 * 4 + 2) * 67 + r] = v.z;
        tile[(c4 * 4 + 3) * 67 + r] = v.w;
    }
    __syncthreads();
    #pragma unroll
    for (int i = 0; i < 2; i++){
        int idx = t + 256 * i;
        int row = idx >> 3, rb = idx & 7;
        f16x8 h;
        #pragma unroll
        for (int j = 0; j < 8; j++) h[j] = (_Float16)tile[row * 67 + rb * 8 + j];
        *(f16x8*)(d + (size_t)(c0 + row) * R + r0 + rb * 8) = h;
    }
}

// ---------------------------------------------------------------------------
// fused_gemm1: unchanged this round (single 268-MB inc pass; ~BW-bound).
// ---------------------------------------------------------------------------
__global__ __launch_bounds__(256, 1) void fused_gemm1(const float* __restrict__ inc,
                                                      const _Float16* __restrict__ featT,
                                                      unsigned long long* __restrict__ bitsX,
                                                      float* __restrict__ p)
{
    __shared__ alignas(16) char smem[36864];   // [0,32K) dense dbuf; [32K,36K) bitsT dbuf

    const int x = blockIdx.x;                  // e-super-block (256 e)
    const int b = blockIdx.y;
    const int z = blockIdx.z;                  // K-slice (1024 m)
    const int t = threadIdx.x, lane = t & 63, w = t >> 6;
    const int fr = lane & 15, q = lane >> 4, q8 = q * 8;

    const int e0 = x * 256;
    const int ew0 = e0 + w * 64;               // this wave's 64-e column group
    const _Float16* dp = featT + (size_t)b * 128 * MM;
    const float* ip = inc + (size_t)b * MM * EE + ew0 + lane;
    unsigned long long* bxp = bitsX + ((size_t)b * 32 + (x * 4 + w)) * MM;

    f32x4 acc[4][8] = {};                      // 64 e-rows x 128 d per wave
    uint4 rd[4];
    float val[64];

    auto loadg = [&](int k0){
        #pragma unroll
        for (int i = 0; i < 4; i++){
            int idx = t + 256 * i;
            int dd = idx >> 3, kb = idx & 7;
            rd[i] = *(const uint4*)(dp + (size_t)dd * MM + k0 + kb * 8);
        }
        const float* rp = ip + (size_t)k0 * EE;
        #pragma unroll
        for (int j = 0; j < 64; j++) val[j] = rp[(size_t)j * EE];
    };
    auto stage = [&](int buf, int k0){
        _Float16* lD = (_Float16*)(smem + buf * 16384);
        unsigned long long* lBits = (unsigned long long*)(smem + 32768 + buf * 2048);
        #pragma unroll
        for (int i = 0; i < 4; i++){
            int idx = t + 256 * i;
            int dd = idx >> 3, kb = idx & 7;
            *(uint4*)&lD[dd * 64 + ((kb ^ (dd & 7)) * 8)] = rd[i];
        }
        // pack: lane j keeps e-bit word of row k0+j
        unsigned long long wbits = 0;
        #pragma unroll
        for (int j = 0; j < 64; j++){
            unsigned long long bal = __ballot(val[j] != 0.0f);
            wbits = (lane == j) ? bal : wbits;
        }
        bxp[k0 + lane] = wbits;                // contiguous 512 B per wave
        // transpose: lane ei keeps m-bit word of e-col ew0+ei
        unsigned long long wT = 0;
        #pragma unroll
        for (int ei = 0; ei < 64; ei++){
            unsigned long long bal = __ballot((wbits >> ei) & 1ull);
            wT = (lane == ei) ? bal : wT;
        }
        lBits[w * 64 + lane] = wT;
    };
    auto compute = [&](int buf){
        const _Float16* lD = (const _Float16*)(smem + buf * 16384);
        const uint2* lBits = (const uint2*)(smem + 32768 + buf * 2048);
        uint2 bw[4];
        f16x8 af[4][2];
        #pragma unroll
        for (int s = 0; s < 4; s++) bw[s] = lBits[w * 64 + s * 16 + fr];
        #pragma unroll
        for (int s = 0; s < 4; s++)
            #pragma unroll
            for (int h = 0; h < 2; h++){
                unsigned word = h ? bw[s].y : bw[s].x;
                unsigned byte = (word >> q8) & 0xFFu;
                #pragma unroll
                for (int j = 0; j < 8; j++)
                    af[s][h][j] = ((byte >> j) & 1u) ? (_Float16)1.0f : (_Float16)0.0f;
            }
        #pragma unroll
        for (int h = 0; h < 2; h++)
            #pragma unroll
            for (int c = 0; c < 8; c++){
                int drow = c * 16 + fr;
                f16x8 bf = *(const f16x8*)&lD[drow * 64 + (((h * 4 + q) ^ (drow & 7)) * 8)];
                #pragma unroll
                for (int s = 0; s < 4; s++)
                    acc[s][c] = __builtin_amdgcn_mfma_f32_16x16x32_f16(af[s][h], bf, acc[s][c], 0, 0, 0);
            }
    };

    const int kbase = z * 1024;
    loadg(kbase); stage(0, kbase); __syncthreads();
    for (int c = 0; c < 16; c++){
        if (c + 1 < 16) loadg(kbase + (c + 1) * 64);   // prefetch under compute
        compute(c & 1);
        if (c + 1 < 16) stage((c + 1) & 1, kbase + (c + 1) * 64);
        __syncthreads();
    }

    // Epilogue: 4 phases; wave ph stages its 64 e-rows, all copy out full lines.
    float* sT = (float*)smem;
    float* op = p + (size_t)z * 2097152 + ((size_t)b * EE + e0) * 128;
    for (int ph = 0; ph < 4; ph++){
        __syncthreads();
        if (w == ph){
            #pragma unroll
            for (int s = 0; s < 4; s++)
                #pragma unroll
                for (int c = 0; c < 8; c++)
                    #pragma unroll
                    for (int reg = 0; reg < 4; reg++)
                        sT[(s * 16 + q * 4 + reg) * 132 + c * 16 + fr] = acc[s][c][reg];
        }
        __syncthreads();
        #pragma unroll
        for (int i = 0; i < 8; i++){
            int idx = t + 256 * i;
            int lrow = idx >> 5, c4 = idx & 31;
            float4 v = *(const float4*)&sT[lrow * 132 + c4 * 4];
            *(float4*)(op + (size_t)(ph * 64 + lrow) * 128 + c4 * 4) = v;
        }
    }
}

// ---------------------------------------------------------------------------
// bitgemm2_fused: Q[m][j] = sum_e bit(m,e)*PT[j][e]; node = Q @ Wc^T.
// NEW: 128 m-rows per block, 2 A-frag sets per wave sharing each B-frag
// -> ds_read_b128 per MFMA halved (was the bottleneck: 12cyc read per 5cyc
// MFMA). Grid (MM/128, BB) = 256 blocks.
// ---------------------------------------------------------------------------
__global__ __launch_bounds__(256) void bitgemm2_fused(const unsigned long long* __restrict__ bitsX,
                                                      const _Float16* __restrict__ PT,
                                                      const _Float16* __restrict__ Wc16,
                                                      float* __restrict__ node)
{
    // [0,32K) dense dbuf; [32K,34K) bits dbuf (2x1K); [34K,66K) Wc; sD=67584
    __shared__ alignas(16) char smem[67584];
    const int b = blockIdx.y;
    const int m0 = blockIdx.x * 128;
    const unsigned long long* bxp = bitsX + (size_t)b * 32 * MM;
    const _Float16* dp = PT + (size_t)b * 128 * EE;
    float* op = node + ((size_t)b * MM + m0) * 128;

    const int t = threadIdx.x, lane = t & 63, w = t >> 6;
    const int fr = lane & 15, q = lane >> 4, q8 = q * 8;

    _Float16* lWc = (_Float16*)(smem + 34816);
    #pragma unroll
    for (int i = 0; i < 8; i++){
        int idx = t + 256 * i;
        int n = idx >> 4, kb = idx & 15;
        *(uint4*)&lWc[n * 128 + ((kb ^ (n & 7)) * 8)] =
            *(const uint4*)(Wc16 + (size_t)n * 128 + kb * 8);
    }

    f32x4 acc[2][8] = {};                      // 2 sets of 16 m-rows x 128 d
    uint4 rd[4];
    unsigned long long rb;

    auto loadg = [&](int kg){
        #pragma unroll
        for (int i = 0; i < 4; i++){
            int idx = t + 256 * i;
            int dd = idx >> 3, kb = idx & 7;
            rd[i] = *(const uint4*)(dp + (size_t)dd * EE + kg + kb * 8);
        }
        if (t < 128) rb = bxp[(size_t)(kg >> 6) * MM + m0 + t];   // contiguous
    };
    auto stage = [&](int buf){
        _Float16* lD = (_Float16*)(smem + buf * 16384);
        unsigned long long* lB = (unsigned long long*)(smem + 32768 + buf * 1024);
        #pragma unroll
        for (int i = 0; i < 4; i++){
            int idx = t + 256 * i;
            int dd = idx >> 3, kb = idx & 7;
            *(uint4*)&lD[dd * 64 + ((kb ^ (dd & 7)) * 8)] = rd[i];
        }
        if (t < 128) lB[t] = rb;
    };
    auto compute = [&](int buf){
        const _Float16* lD = (const _Float16*)(smem + buf * 16384);
        const uint2* lB = (const uint2*)(smem + 32768 + buf * 1024);
        uint2 bw0 = lB[w * 32 + fr];
        uint2 bw1 = lB[w * 32 + 16 + fr];
        #pragma unroll
        for (int h = 0; h < 2; h++){
            unsigned word0 = h ? bw0.y : bw0.x;
            unsigned word1 = h ? bw1.y : bw1.x;
            unsigned byte0 = (word0 >> q8) & 0xFFu;
            unsigned byte1 = (word1 >> q8) & 0xFFu;
            f16x8 af0, af1;
            #pragma unroll
            for (int j = 0; j < 8; j++){
                af0[j] = ((byte0 >> j) & 1u) ? (_Float16)1.0f : (_Float16)0.0f;
                af1[j] = ((byte1 >> j) & 1u) ? (_Float16)1.0f : (_Float16)0.0f;
            }
            #pragma unroll
            for (int c = 0; c < 8; c++){
                int drow = c * 16 + fr;
                f16x8 bf = *(const f16x8*)&lD[drow * 64 + (((h * 4 + q) ^ (drow & 7)) * 8)];
                acc[0][c] = __builtin_amdgcn_mfma_f32_16x16x32_f16(af0, bf, acc[0][c], 0, 0, 0);
                acc[1][c] = __builtin_amdgcn_mfma_f32_16x16x32_f16(af1, bf, acc[1][c], 0, 0, 0);
            }
        }
    };

    loadg(0); stage(0); __syncthreads();
    for (int c = 0; c < 32; c++){
        if (c + 1 < 32) loadg((c + 1) * 64);
        compute(c & 1);
        if (c + 1 < 32) stage((c + 1) & 1);
        __syncthreads();
    }

    // Phase 2: Q (f16, per-wave-private rows) @ Wc^T via MFMA.
    _Float16* sQ = (_Float16*)smem;
    #pragma unroll
    for (int u = 0; u < 2; u++)
        #pragma unroll
        for (int c = 0; c < 8; c++)
            #pragma unroll
            for (int reg = 0; reg < 4; reg++){
                int row = w * 32 + u * 16 + q * 4 + reg;
                int col = c * 16 + fr;
                sQ[row * 128 + (((col >> 3) ^ (row & 7)) * 8) + (col & 7)] = (_Float16)acc[u][c][reg];
            }
    f32x4 acc2[2][8] = {};
    #pragma unroll
    for (int kk = 0; kk < 4; kk++){
        int arow0 = w * 32 + fr;
        int arow1 = w * 32 + 16 + fr;
        f16x8 a20 = *(const f16x8*)&sQ[arow0 * 128 + (((kk * 4 + q) ^ (arow0 & 7)) * 8)];
        f16x8 a21 = *(const f16x8*)&sQ[arow1 * 128 + (((kk * 4 + q) ^ (arow1 & 7)) * 8)];
        #pragma unroll
        for (int c = 0; c < 8; c++){
            int n = c * 16 + fr;
            f16x8 b2 = *(const f16x8*)&lWc[n * 128 + (((kk * 4 + q) ^ (n & 7)) * 8)];
            acc2[0][c] = __builtin_amdgcn_mfma_f32_16x16x32_f16(a20, b2, acc2[0][c], 0, 0, 0);
            acc2[1][c] = __builtin_amdgcn_mfma_f32_16x16x32_f16(a21, b2, acc2[1][c], 0, 0, 0);
        }
    }
    __syncthreads();
    float* sD = (float*)smem;                  // 128 x 132 f32 = 67584 B
    #pragma unroll
    for (int u = 0; u < 2; u++)
        #pragma unroll
        for (int c = 0; c < 8; c++)
            #pragma unroll
            for (int reg = 0; reg < 4; reg++)
                sD[(w * 32 + u * 16 + q * 4 + reg) * 132 + c * 16 + fr] = acc2[u][c][reg];
    __syncthreads();
    #pragma unroll
    for (int i = 0; i < 16; i++){
        int idx = t + 256 * i;
        int lrow = idx >> 5, c4 = idx & 31;
        float4 v = *(const float4*)&sD[lrow * 132 + c4 * 4];
        *(float4*)(op + (size_t)lrow * 128 + c4 * 4) = v;
    }
}

// ---------------------------------------------------------------------------
// rowmm_sum4: A = p0+p1+p2+p3; A -> aggOut (aliases p0, safe) and
// C = A @ W^T -> C.  NEW: 64 rows/block, 4x4 register blocking
// (8 b128 reads / 128 FMA vs 12/64) + XOR k-group swizzle so the 4-row
// strided lW column reads hit distinct bank windows (was 8-way conflict).
// ---------------------------------------------------------------------------
__global__ __launch_bounds__(256) void rowmm_sum4(const float* __restrict__ p,
                                                  const float* __restrict__ W,
                                                  float* aggOut,
                                                  float* __restrict__ C)
{
    __shared__ alignas(16) float lA[64][132];
    __shared__ alignas(16) float lW[64][132];
    const int t = threadIdx.x;
    const int row0 = blockIdx.x * 64;
    const float4* P4 = (const float4*)p;
    const float4* W4 = (const float4*)W;
    float4* A4 = (float4*)aggOut;
    const size_t SS = 2097152 / 4;

    #pragma unroll
    for (int i = 0; i < 8; i++){
        int idx = t + 256 * i;
        int r = idx >> 5, k4 = idx & 31;
        size_t gi = (size_t)(row0 + r) * 32 + k4;
        float4 a = P4[gi], b = P4[gi + SS], c = P4[gi + 2 * SS], d = P4[gi + 3 * SS];
        float4 s = make_float4(a.x + b.x + c.x + d.x, a.y + b.y + c.y + d.y,
                               a.z + b.z + c.z + d.z, a.w + b.w + c.w + d.w);
        *(float4*)&lA[r][((k4 ^ (r >> 3)) & 31) * 4] = s;
        A4[gi] = s;
    }
    const int rr = t >> 4, cg = t & 15;
    const int keyA = rr >> 1, keyW = cg >> 1;

    #pragma unroll
    for (int ph = 0; ph < 2; ph++){
        __syncthreads();
        #pragma unroll
        for (int i = 0; i < 8; i++){
            int idx = t + 256 * i;
            int cN = idx >> 5, k4 = idx & 31;
            *(float4*)&lW[cN][((k4 ^ (cN >> 3)) & 31) * 4] = W4[(size_t)(ph * 64 + cN) * 32 + k4];
        }
        __syncthreads();
        float s[4][4] = {};
        for (int k4 = 0; k4 < 32; k4++){
            float4 wv[4];
            #pragma unroll
            for (int jc = 0; jc < 4; jc++)
                wv[jc] = *(const float4*)&lW[cg * 4 + jc][((k4 ^ keyW) & 31) * 4];
            #pragma unroll
            for (int i = 0; i < 4; i++){
                float4 a = *(const float4*)&lA[rr * 4 + i][((k4 ^ keyA) & 31) * 4];
                #pragma unroll
                for (int jc = 0; jc < 4; jc++)
                    s[i][jc] += a.x * wv[jc].x + a.y * wv[jc].y + a.z * wv[jc].z + a.w * wv[jc].w;
            }
        }
        #pragma unroll
        for (int i = 0; i < 4; i++)
            *(float4*)&C[(size_t)(row0 + rr * 4 + i) * DD + ph * 64 + cg * 4] =
                make_float4(s[i][0], s[i][1], s[i][2], s[i][3]);
    }
}

// ---------------------------------------------------------------------------
// rowmm: C[n,:] = A[n,:] @ W^T, fp32. Same 4x4 blocking as rowmm_sum4.
// ---------------------------------------------------------------------------
__global__ __launch_bounds__(256) void rowmm(const float* A,
                                             const float* __restrict__ W,
                                             float* C)
{
    __shared__ alignas(16) float lA[64][132];
    __shared__ alignas(16) float lW[64][132];
    const int t = threadIdx.x;
    const int row0 = blockIdx.x * 64;
    const float4* A4 = (const float4*)A;
    const float4* W4 = (const float4*)W;

    #pragma unroll
    for (int i = 0; i < 8; i++){
        int idx = t + 256 * i;
        int r = idx >> 5, k4 = idx & 31;
        *(float4*)&lA[r][((k4 ^ (r >> 3)) & 31) * 4] = A4[(size_t)(row0 + r) * 32 + k4];
    }
    const int rr = t >> 4, cg = t & 15;
    const int keyA = rr >> 1, keyW = cg >> 1;

    #pragma unroll
    for (int ph = 0; ph < 2; ph++){
        __syncthreads();
        #pragma unroll
        for (int i = 0; i < 8; i++){
            int idx = t + 256 * i;
            int cN = idx >> 5, k4 = idx & 31;
            *(float4*)&lW[cN][((k4 ^ (cN >> 3)) & 31) * 4] = W4[(size_t)(ph * 64 + cN) * 32 + k4];
        }
        __syncthreads();
        float s[4][4] = {};
        for (int k4 = 0; k4 < 32; k4++){
            float4 wv[4];
            #pragma unroll
            for (int jc = 0; jc < 4; jc++)
                wv[jc] = *(const float4*)&lW[cg * 4 + jc][((k4 ^ keyW) & 31) * 4];
            #pragma unroll
            for (int i = 0; i < 4; i++){
                float4 a = *(const float4*)&lA[rr * 4 + i][((k4 ^ keyA) & 31) * 4];
                #pragma unroll
                for (int jc = 0; jc < 4; jc++)
                    s[i][jc] += a.x * wv[jc].x + a.y * wv[jc].y + a.z * wv[jc].z + a.w * wv[jc].w;
            }
        }
        #pragma unroll
        for (int i = 0; i < 4; i++)
            *(float4*)&C[(size_t)(row0 + rr * 4 + i) * DD + ph * 64 + cg * 4] =
                make_float4(s[i][0], s[i][1], s[i][2], s[i][3]);
    }
}

// ---------------------------------------------------------------------------
// wc_mm16: Wc16 = f16(eWp @ vWp)  (128x128x128)
// ---------------------------------------------------------------------------
__global__ __launch_bounds__(256) void wc_mm16(const float* __restrict__ eWp,
                                               const float* __restrict__ vWp,
                                               _Float16* __restrict__ Wc16)
{
    int i = blockIdx.x * 2 + (threadIdx.x >> 7);
    int j = threadIdx.x & 127;
    float acc = 0.f;
    for (int k = 0; k < 128; k++)
        acc += eWp[i * 128 + k] * vWp[k * 128 + j];
    Wc16[i * 128 + j] = (_Float16)acc;
}

// ---------------------------------------------------------------------------
// Online softmax over e. NEW sm_part: single global pass — 64 values held in
// registers, max AND sum from regs (slab = 128 e, grid (BB,16)).
// ---------------------------------------------------------------------------
__global__ __launch_bounds__(256) void sm_part(const float* __restrict__ eatt,
                                               float* __restrict__ part)
{
    const int b = blockIdx.x, slab = blockIdx.y;
    const int t = threadIdx.x;
    const int dl = t & 127, eh = t >> 7;
    const size_t base = (size_t)b * EE * DD + dl;
    const int e0 = slab * 128;
    float v[64];
    #pragma unroll
    for (int s = 0; s < 64; s++)
        v[s] = eatt[base + (size_t)(e0 + eh + 2 * s) * DD];
    float m = -1e30f;
    #pragma unroll
    for (int s = 0; s < 64; s++) m = fmaxf(m, v[s]);
    float l = 0.f;
    #pragma unroll
    for (int s = 0; s < 64; s++) l += __expf(v[s] - m);
    __shared__ float red[2][128][2];
    red[eh][dl][0] = m; red[eh][dl][1] = l;
    __syncthreads();
    if (t < 128){
        float m0 = red[0][t][0], l0 = red[0][t][1];
        float m1 = red[1][t][0], l1 = red[1][t][1];
        float M = fmaxf(m0, m1);
        float L = l0 * __expf(m0 - M) + l1 * __expf(m1 - M);
        float* pp = part + ((size_t)(b * 16 + slab) * DD + t) * 2;
        pp[0] = M; pp[1] = L;
    }
}

__global__ __launch_bounds__(256) void sm_apply(float* __restrict__ eatt,
                                                const float* __restrict__ agg,
                                                const float* __restrict__ part)
{
    const int b = blockIdx.x, sl = blockIdx.y;
    const int t = threadIdx.x;
    __shared__ float mv[128], iv[128];
    if (t < 128){
        float mbuf[16], lbuf[16];
        float M = -1e30f;
        #pragma unroll
        for (int s = 0; s < 16; s++){
            const float* pp = part + ((size_t)(b * 16 + s) * DD + t) * 2;
            mbuf[s] = pp[0]; lbuf[s] = pp[1];
            M = fmaxf(M, mbuf[s]);
        }
        float L = 0.f;
        #pragma unroll
        for (int s = 0; s < 16; s++) L += lbuf[s] * __expf(mbuf[s] - M);
        mv[t] = M; iv[t] = 1.f / L;
    }
    __syncthreads();
    const int dl = t & 127, eh = t >> 7;
    const size_t base = (size_t)b * EE * DD + dl;
    const int e0 = sl * 128;
    for (int s = 0; s < 64; s++){
        size_t ix = base + (size_t)(e0 + eh + 2 * s) * DD;
        eatt[ix] = agg[ix] * __expf(eatt[ix] - mv[dl]) * iv[dl];
    }
}

// ---------------------------------------------------------------------------
// Pipeline (layer recursion = fixed point; ec_Wa dead):
//  1. featT = T(feat) f16 ; Wc16 = f16(eWp@vWp)
//  2. fused_gemm1: ONE inc pass -> p0..p3 (split-K agg) + bitsX
//  3. agg = sum p ; eatt = agg@vWa^T (fused)
//  4. softmax -> P (in-place)
//  5. edge = P@vWp^T (OUT2); PT = T(P) f16
//  6. node = (inc@P)@Wc^T fused bitgemm2 (OUT1)
// ws: [0,8M)=bitsX; [8,40M)=p0..p3 (agg over p0, PT over p1); [40M)=Wc16.
// d_out: node[0,8M)=featT; node[8,16M)=eatt/P; edge=part->edge.
// ---------------------------------------------------------------------------
extern "C" void kernel_launch(void* const* d_in, const int* in_sizes, int n_in,
                              void* d_out, int out_size, void* d_ws, size_t ws_size,
                              hipStream_t stream)
{
    const float* feat = (const float*)d_in[0];
    const float* inc  = (const float*)d_in[1];
    const float* vWa  = (const float*)d_in[2];
    const float* vWp  = (const float*)d_in[3];
    const float* eWp  = (const float*)d_in[6];

    float* node_out = (float*)d_out;
    float* edge_out = node_out + (size_t)BB * MM * DD;

    char* w = (char*)d_ws;
    unsigned long long* bitsX = (unsigned long long*)w;        // [0,8M)
    float* pk  = (float*)(w + ((size_t)8 << 20));              // p0..p3 (8 MB each)
    float* agg = pk;                                           // over p0
    _Float16* PT = (_Float16*)(w + ((size_t)16 << 20));        // over p1 (dead after sum4)
    _Float16* Wc16 = (_Float16*)(w + ((size_t)40 << 20));

    _Float16* featT = (_Float16*)node_out;                     // node[0,8M)
    float* eattP = node_out + 2097152;                         // node[8,16M)
    float* part  = edge_out;                                   // dead before edge

    dim3 blk(256);

    // 1. featT + Wc16
    transpose_to16<<<dim3((MM / 64) * (DD / 64), BB), blk, 0, stream>>>(feat, featT, MM, DD);
    wc_mm16<<<dim3(64), blk, 0, stream>>>(eWp, vWp, Wc16);
    // 2. one inc pass: p partials + bitsX
    fused_gemm1<<<dim3(EE / 256, BB, 4), blk, 0, stream>>>(inc, featT, bitsX, pk);
    // 3. agg = sum p ; eatt = agg @ vWa^T
    rowmm_sum4<<<dim3(BB * EE / 64), blk, 0, stream>>>(pk, vWa, agg, eattP);
    // 4. P = agg * softmax_e(eatt)
    sm_part <<<dim3(BB, 16), blk, 0, stream>>>(eattP, part);
    sm_apply<<<dim3(BB, 16), blk, 0, stream>>>(eattP, agg, part);
    // 5. edge = P @ vWp^T (OUT2); PT = f16(P^T)
    rowmm<<<dim3(BB * EE / 64), blk, 0, stream>>>(eattP, vWp, edge_out);
    transpose_to16<<<dim3((EE / 64) * (DD / 64), BB), blk, 0, stream>>>(eattP, PT, EE, DD);
    // 6. node = (inc@P) @ Wc^T fused (OUT1)
    bitgemm2_fused<<<dim3(MM / 128, BB), blk, 0, stream>>>(bitsX, PT, Wc16, node_out);
}

// Round 2
// 516.454 us; speedup vs baseline: 1.0945x; 1.0244x over previous
//
#include <hip/hip_runtime.h>

#define BB 8
#define MM 4096
#define EE 2048
#define DD 128

typedef _Float16 f16x8 __attribute__((ext_vector_type(8)));
typedef float    f32x4 __attribute__((ext_vector_type(4)));

// ---------------------------------------------------------------------------
// prep: blocks [0,1024) transpose feat [4096][128] f32 -> featT [128][4096] f16
//       blocks [1024,1088) compute Wc16 = f16(eWp @ vWp) (128x128x128)
// ---------------------------------------------------------------------------
__global__ __launch_bounds__(256) void prep(const float* __restrict__ feat,
                                            _Float16* __restrict__ featT,
                                            const float* __restrict__ eWp,
                                            const float* __restrict__ vWp,
                                            _Float16* __restrict__ Wc16)
{
    __shared__ alignas(16) float tile[64 * 67];
    const int t = threadIdx.x;
    if (blockIdx.x >= 1024){
        int i = (blockIdx.x - 1024) * 2 + (t >> 7);
        int j = t & 127;
        float acc = 0.f;
        for (int k = 0; k < 128; k++)
            acc += eWp[i * 128 + k] * vWp[k * 128 + j];
        Wc16[i * 128 + j] = (_Float16)acc;
        return;
    }
    const int b = blockIdx.x >> 7, tl = blockIdx.x & 127;
    const int r0 = (tl >> 1) << 6;          // tilesC = DD/64 = 2
    const int c0 = (tl & 1) << 6;
    const float* s = feat + (size_t)b * MM * DD;
    _Float16*   d = featT + (size_t)b * MM * DD;
    #pragma unroll
    for (int i = 0; i < 4; i++){
        int idx = t + 256 * i;
        int r = idx >> 4, c4 = idx & 15;
        float4 v = *(const float4*)(s + (size_t)(r0 + r) * DD + c0 + c4 * 4);
        tile[(c4 * 4 + 0) * 67 + r] = v.x;
        tile[(c4 * 4 + 1) * 67 + r] = v.y;
        tile[(c4 * 4 + 2) * 67 + r] = v.z;
        tile[(c4 * 4 + 3) * 67 + r] = v.w;
    }
    __syncthreads();
    #pragma unroll
    for (int i = 0; i < 2; i++){
        int idx = t + 256 * i;
        int row = idx >> 3, rb = idx & 7;
        f16x8 h;
        #pragma unroll
        for (int j = 0; j < 8; j++) h[j] = (_Float16)tile[row * 67 + rb * 8 + j];
        *(f16x8*)(d + (size_t)(c0 + row) * MM + r0 + rb * 8) = h;
    }
}

// ---------------------------------------------------------------------------
// fused_gemm1: single 268-MB inc pass -> p split-K partials + bitsX.
// NEW: XCD-affinity decode — the 8 e-blocks sharing a (b,z) featT slice get
// the same (id % 8), so the 256-KB slice is read ~once per XCD from HBM.
// ---------------------------------------------------------------------------
__global__ __launch_bounds__(256, 1) void fused_gemm1(const float* __restrict__ inc,
                                                      const _Float16* __restrict__ featT,
                                                      unsigned long long* __restrict__ bitsX,
                                                      float* __restrict__ p)
{
    __shared__ alignas(16) char smem[36864];   // [0,32K) dense dbuf; [32K,36K) bitsT dbuf

    const int id = blockIdx.x;
    const int s_ = id >> 3;
    const int x  = s_ & 7;                      // e-super-block (256 e)
    const int pair = (id & 7) * 4 + (s_ >> 3);  // (b,z) group, constant XCD
    const int b = pair & 7, z = pair >> 3;

    const int t = threadIdx.x, lane = t & 63, w = t >> 6;
    const int fr = lane & 15, q = lane >> 4, q8 = q * 8;

    const int e0 = x * 256;
    const int ew0 = e0 + w * 64;               // this wave's 64-e column group
    const _Float16* dp = featT + (size_t)b * 128 * MM;
    const float* ip = inc + (size_t)b * MM * EE + ew0 + lane;
    unsigned long long* bxp = bitsX + ((size_t)b * 32 + (x * 4 + w)) * MM;

    f32x4 acc[4][8] = {};                      // 64 e-rows x 128 d per wave
    uint4 rd[4];
    float val[64];

    auto loadg = [&](int k0){
        #pragma unroll
        for (int i = 0; i < 4; i++){
            int idx = t + 256 * i;
            int dd = idx >> 3, kb = idx & 7;
            rd[i] = *(const uint4*)(dp + (size_t)dd * MM + k0 + kb * 8);
        }
        const float* rp = ip + (size_t)k0 * EE;
        #pragma unroll
        for (int j = 0; j < 64; j++) val[j] = rp[(size_t)j * EE];
    };
    auto stage = [&](int buf, int k0){
        _Float16* lD = (_Float16*)(smem + buf * 16384);
        unsigned long long* lBits = (unsigned long long*)(smem + 32768 + buf * 2048);
        #pragma unroll
        for (int i = 0; i < 4; i++){
            int idx = t + 256 * i;
            int dd = idx >> 3, kb = idx & 7;
            *(uint4*)&lD[dd * 64 + ((kb ^ (dd & 7)) * 8)] = rd[i];
        }
        // pack: lane j keeps e-bit word of row k0+j
        unsigned long long wbits = 0;
        #pragma unroll
        for (int j = 0; j < 64; j++){
            unsigned long long bal = __ballot(val[j] != 0.0f);
            wbits = (lane == j) ? bal : wbits;
        }
        bxp[k0 + lane] = wbits;                // contiguous 512 B per wave
        // transpose: lane ei keeps m-bit word of e-col ew0+ei
        unsigned long long wT = 0;
        #pragma unroll
        for (int ei = 0; ei < 64; ei++){
            unsigned long long bal = __ballot((wbits >> ei) & 1ull);
            wT = (lane == ei) ? bal : wT;
        }
        lBits[w * 64 + lane] = wT;
    };
    auto compute = [&](int buf){
        const _Float16* lD = (const _Float16*)(smem + buf * 16384);
        const uint2* lBits = (const uint2*)(smem + 32768 + buf * 2048);
        uint2 bw[4];
        f16x8 af[4][2];
        #pragma unroll
        for (int s = 0; s < 4; s++) bw[s] = lBits[w * 64 + s * 16 + fr];
        #pragma unroll
        for (int s = 0; s < 4; s++)
            #pragma unroll
            for (int h = 0; h < 2; h++){
                unsigned word = h ? bw[s].y : bw[s].x;
                unsigned byte = (word >> q8) & 0xFFu;
                #pragma unroll
                for (int j = 0; j < 8; j++)
                    af[s][h][j] = ((byte >> j) & 1u) ? (_Float16)1.0f : (_Float16)0.0f;
            }
        #pragma unroll
        for (int h = 0; h < 2; h++)
            #pragma unroll
            for (int c = 0; c < 8; c++){
                int drow = c * 16 + fr;
                f16x8 bf = *(const f16x8*)&lD[drow * 64 + (((h * 4 + q) ^ (drow & 7)) * 8)];
                #pragma unroll
                for (int s = 0; s < 4; s++)
                    acc[s][c] = __builtin_amdgcn_mfma_f32_16x16x32_f16(af[s][h], bf, acc[s][c], 0, 0, 0);
            }
    };

    const int kbase = z * 1024;
    loadg(kbase); stage(0, kbase); __syncthreads();
    for (int c = 0; c < 16; c++){
        if (c + 1 < 16) loadg(kbase + (c + 1) * 64);   // prefetch under compute
        compute(c & 1);
        if (c + 1 < 16) stage((c + 1) & 1, kbase + (c + 1) * 64);
        __syncthreads();
    }

    // Epilogue: 4 phases; wave ph stages its 64 e-rows, all copy out full lines.
    float* sT = (float*)smem;
    float* op = p + (size_t)z * 2097152 + ((size_t)b * EE + e0) * 128;
    for (int ph = 0; ph < 4; ph++){
        __syncthreads();
        if (w == ph){
            #pragma unroll
            for (int s = 0; s < 4; s++)
                #pragma unroll
                for (int c = 0; c < 8; c++)
                    #pragma unroll
                    for (int reg = 0; reg < 4; reg++)
                        sT[(s * 16 + q * 4 + reg) * 132 + c * 16 + fr] = acc[s][c][reg];
        }
        __syncthreads();
        #pragma unroll
        for (int i = 0; i < 8; i++){
            int idx = t + 256 * i;
            int lrow = idx >> 5, c4 = idx & 31;
            float4 v = *(const float4*)&sT[lrow * 132 + c4 * 4];
            *(float4*)(op + (size_t)(ph * 64 + lrow) * 128 + c4 * 4) = v;
        }
    }
}

// ---------------------------------------------------------------------------
// rowmm_sum4_sm: A = p0+p1+p2+p3 -> aggOut; eatt = A @ W^T -> C; PLUS per-
// block online-softmax partials (m, sum exp) per d-column over the block's
// 64 e-rows, straight from the GEMM registers -> part[blk][128][2].
// Kills the separate sm_part kernel and its 8-MB re-read.
// ---------------------------------------------------------------------------
__global__ __launch_bounds__(256) void rowmm_sum4_sm(const float* __restrict__ p,
                                                     const float* __restrict__ W,
                                                     float* aggOut,
                                                     float* __restrict__ C,
                                                     float* __restrict__ part)
{
    __shared__ alignas(16) float lA[64][132];
    __shared__ alignas(16) float lW[64][132];
    __shared__ alignas(16) float red[16][64];
    __shared__ alignas(16) float colm[64];
    const int t = threadIdx.x;
    const int row0 = blockIdx.x * 64;
    const float4* P4 = (const float4*)p;
    const float4* W4 = (const float4*)W;
    float4* A4 = (float4*)aggOut;
    const size_t SS = 2097152 / 4;

    #pragma unroll
    for (int i = 0; i < 8; i++){
        int idx = t + 256 * i;
        int r = idx >> 5, k4 = idx & 31;
        size_t gi = (size_t)(row0 + r) * 32 + k4;
        float4 a = P4[gi], b = P4[gi + SS], c = P4[gi + 2 * SS], d = P4[gi + 3 * SS];
        float4 s = make_float4(a.x + b.x + c.x + d.x, a.y + b.y + c.y + d.y,
                               a.z + b.z + c.z + d.z, a.w + b.w + c.w + d.w);
        *(float4*)&lA[r][((k4 ^ (r >> 3)) & 31) * 4] = s;
        A4[gi] = s;
    }
    const int rr = t >> 4, cg = t & 15;
    const int keyA = rr >> 1, keyW = cg >> 1;

    #pragma unroll
    for (int ph = 0; ph < 2; ph++){
        __syncthreads();
        #pragma unroll
        for (int i = 0; i < 8; i++){
            int idx = t + 256 * i;
            int cN = idx >> 5, k4 = idx & 31;
            *(float4*)&lW[cN][((k4 ^ (cN >> 3)) & 31) * 4] = W4[(size_t)(ph * 64 + cN) * 32 + k4];
        }
        __syncthreads();
        float s[4][4] = {};
        for (int k4 = 0; k4 < 32; k4++){
            float4 wv[4];
            #pragma unroll
            for (int jc = 0; jc < 4; jc++)
                wv[jc] = *(const float4*)&lW[cg * 4 + jc][((k4 ^ keyW) & 31) * 4];
            #pragma unroll
            for (int i = 0; i < 4; i++){
                float4 a = *(const float4*)&lA[rr * 4 + i][((k4 ^ keyA) & 31) * 4];
                #pragma unroll
                for (int jc = 0; jc < 4; jc++)
                    s[i][jc] += a.x * wv[jc].x + a.y * wv[jc].y + a.z * wv[jc].z + a.w * wv[jc].w;
            }
        }
        #pragma unroll
        for (int i = 0; i < 4; i++)
            *(float4*)&C[(size_t)(row0 + rr * 4 + i) * DD + ph * 64 + cg * 4] =
                make_float4(s[i][0], s[i][1], s[i][2], s[i][3]);

        // --- softmax partials for this phase's 64 d-columns ---
        {
            float4 mt = make_float4(
                fmaxf(fmaxf(s[0][0], s[1][0]), fmaxf(s[2][0], s[3][0])),
                fmaxf(fmaxf(s[0][1], s[1][1]), fmaxf(s[2][1], s[3][1])),
                fmaxf(fmaxf(s[0][2], s[1][2]), fmaxf(s[2][2], s[3][2])),
                fmaxf(fmaxf(s[0][3], s[1][3]), fmaxf(s[2][3], s[3][3])));
            *(float4*)&red[rr][cg * 4] = mt;
        }
        __syncthreads();
        if (t < 64){
            float m = -1e30f;
            #pragma unroll
            for (int r2 = 0; r2 < 16; r2++) m = fmaxf(m, red[r2][t]);
            colm[t] = m;
        }
        __syncthreads();
        {
            float4 cm = *(const float4*)&colm[cg * 4];
            float4 st;
            st.x = __expf(s[0][0]-cm.x) + __expf(s[1][0]-cm.x) + __expf(s[2][0]-cm.x) + __expf(s[3][0]-cm.x);
            st.y = __expf(s[0][1]-cm.y) + __expf(s[1][1]-cm.y) + __expf(s[2][1]-cm.y) + __expf(s[3][1]-cm.y);
            st.z = __expf(s[0][2]-cm.z) + __expf(s[1][2]-cm.z) + __expf(s[2][2]-cm.z) + __expf(s[3][2]-cm.z);
            st.w = __expf(s[0][3]-cm.w) + __expf(s[1][3]-cm.w) + __expf(s[2][3]-cm.w) + __expf(s[3][3]-cm.w);
            *(float4*)&red[rr][cg * 4] = st;
        }
        __syncthreads();
        if (t < 64){
            float l = 0.f;
            #pragma unroll
            for (int r2 = 0; r2 < 16; r2++) l += red[r2][t];
            float* pp = part + ((size_t)blockIdx.x * 128 + ph * 64 + t) * 2;
            pp[0] = colm[t]; pp[1] = l;
        }
    }
}

// ---------------------------------------------------------------------------
// apply_edge_pt: per block = 64 e-rows of one batch.
//   1. combine 32 softmax partials -> (m, 1/L) per d
//   2. P = agg * exp(eatt - m) / L   (registers -> LDS, never to HBM)
//   3. PT f16 transposed write (for bitgemm2)
//   4. edge = P @ vWp^T (fp32, 4x4-blocked)
// Replaces sm_apply + rowmm + transpose_to16(P): 3 kernels -> 1.
// ---------------------------------------------------------------------------
__global__ __launch_bounds__(256) void apply_edge_pt(const float* __restrict__ eatt,
                                                     const float* __restrict__ agg,
                                                     const float* __restrict__ part,
                                                     const float* __restrict__ W,
                                                     float* __restrict__ edge,
                                                     _Float16* __restrict__ PT)
{
    __shared__ alignas(16) float lA[64][132];
    __shared__ alignas(16) float lW[64][132];
    __shared__ alignas(16) float mv[128];
    __shared__ alignas(16) float iv[128];
    const int t = threadIdx.x;
    const int b = blockIdx.x >> 5;
    const int sl = blockIdx.x & 31;
    const int e0g = sl * 64;

    // 1. combine partials (32 slabs of this batch)
    if (t < 128){
        float M = -1e30f, L = 0.f;
        for (int s = 0; s < 32; s++){
            const float* pp = part + ((size_t)(b * 32 + s) * 128 + t) * 2;
            float m = pp[0], l = pp[1];
            float nM = fmaxf(M, m);
            L = L * __expf(M - nM) + l * __expf(m - nM);
            M = nM;
        }
        mv[t] = M; iv[t] = 1.f / L;
    }
    __syncthreads();

    // 2. P rows -> lA (swizzled like rowmm's A tile)
    const float4* AG4 = (const float4*)(agg  + ((size_t)b * EE + e0g) * DD);
    const float4* ET4 = (const float4*)(eatt + ((size_t)b * EE + e0g) * DD);
    const int k4c = t & 31;
    float4 mv4 = *(const float4*)&mv[k4c * 4];
    float4 iv4 = *(const float4*)&iv[k4c * 4];
    #pragma unroll
    for (int i = 0; i < 8; i++){
        int idx = t + 256 * i;
        int r = idx >> 5;
        size_t gi = (size_t)r * 32 + k4c;
        float4 av = AG4[gi], ev = ET4[gi];
        float4 pv = make_float4(av.x * __expf(ev.x - mv4.x) * iv4.x,
                                av.y * __expf(ev.y - mv4.y) * iv4.y,
                                av.z * __expf(ev.z - mv4.z) * iv4.z,
                                av.w * __expf(ev.w - mv4.w) * iv4.w);
        *(float4*)&lA[r][((k4c ^ (r >> 3)) & 31) * 4] = pv;
    }
    __syncthreads();

    // 3. PT[d][e] = f16(P[e][d]) — column reads from lA (2-way bank alias only)
    {
        int d = t >> 1, half = t & 1;
        _Float16* pt = PT + (size_t)b * DD * EE + (size_t)d * EE + e0g + half * 32;
        #pragma unroll
        for (int g = 0; g < 4; g++){
            f16x8 hv;
            #pragma unroll
            for (int j = 0; j < 8; j++){
                int e = half * 32 + g * 8 + j;
                hv[j] = (_Float16)lA[e][(((d >> 2) ^ (e >> 3)) & 31) * 4 + (d & 3)];
            }
            *(f16x8*)(pt + g * 8) = hv;
        }
    }

    // 4. edge = P @ W^T
    const float4* W4 = (const float4*)W;
    const int rr = t >> 4, cg = t & 15;
    const int keyA = rr >> 1, keyW = cg >> 1;
    float* C = edge + ((size_t)b * EE + e0g) * DD;
    #pragma unroll
    for (int ph = 0; ph < 2; ph++){
        __syncthreads();
        #pragma unroll
        for (int i = 0; i < 8; i++){
            int idx = t + 256 * i;
            int cN = idx >> 5, k4 = idx & 31;
            *(float4*)&lW[cN][((k4 ^ (cN >> 3)) & 31) * 4] = W4[(size_t)(ph * 64 + cN) * 32 + k4];
        }
        __syncthreads();
        float s[4][4] = {};
        for (int k4 = 0; k4 < 32; k4++){
            float4 wv[4];
            #pragma unroll
            for (int jc = 0; jc < 4; jc++)
                wv[jc] = *(const float4*)&lW[cg * 4 + jc][((k4 ^ keyW) & 31) * 4];
            #pragma unroll
            for (int i = 0; i < 4; i++){
                float4 a = *(const float4*)&lA[rr * 4 + i][((k4 ^ keyA) & 31) * 4];
                #pragma unroll
                for (int jc = 0; jc < 4; jc++)
                    s[i][jc] += a.x * wv[jc].x + a.y * wv[jc].y + a.z * wv[jc].z + a.w * wv[jc].w;
            }
        }
        #pragma unroll
        for (int i = 0; i < 4; i++)
            *(float4*)&C[(size_t)(rr * 4 + i) * DD + ph * 64 + cg * 4] =
                make_float4(s[i][0], s[i][1], s[i][2], s[i][3]);
    }
}

// ---------------------------------------------------------------------------
// bitgemm2_fused: Q[m][j] = sum_e bit(m,e)*PT[j][e]; node = Q @ Wc^T.
// NEW: XCD-affinity decode — all 32 m-blocks of batch b share (id % 8), so
// b's 512-KB PT slice + 1-MB bits stay in one XCD's L2.
// ---------------------------------------------------------------------------
__global__ __launch_bounds__(256) void bitgemm2_fused(const unsigned long long* __restrict__ bitsX,
                                                      const _Float16* __restrict__ PT,
                                                      const _Float16* __restrict__ Wc16,
                                                      float* __restrict__ node)
{
    // [0,32K) dense dbuf; [32K,34K) bits dbuf (2x1K); [34K,66K) Wc; sD=67584
    __shared__ alignas(16) char smem[67584];
    const int b = blockIdx.x & 7;
    const int m0 = (blockIdx.x >> 3) * 128;
    const unsigned long long* bxp = bitsX + (size_t)b * 32 * MM;
    const _Float16* dp = PT + (size_t)b * 128 * EE;
    float* op = node + ((size_t)b * MM + m0) * 128;

    const int t = threadIdx.x, lane = t & 63, w = t >> 6;
    const int fr = lane & 15, q = lane >> 4, q8 = q * 8;

    _Float16* lWc = (_Float16*)(smem + 34816);
    #pragma unroll
    for (int i = 0; i < 8; i++){
        int idx = t + 256 * i;
        int n = idx >> 4, kb = idx & 15;
        *(uint4*)&lWc[n * 128 + ((kb ^ (n & 7)) * 8)] =
            *(const uint4*)(Wc16 + (size_t)n * 128 + kb * 8);
    }

    f32x4 acc[2][8] = {};                      // 2 sets of 16 m-rows x 128 d
    uint4 rd[4];
    unsigned long long rb;

    auto loadg = [&](int kg){
        #pragma unroll
        for (int i = 0; i < 4; i++){
            int idx = t + 256 * i;
            int dd = idx >> 3, kb = idx & 7;
            rd[i] = *(const uint4*)(dp + (size_t)dd * EE + kg + kb * 8);
        }
        if (t < 128) rb = bxp[(size_t)(kg >> 6) * MM + m0 + t];   // contiguous
    };
    auto stage = [&](int buf){
        _Float16* lD = (_Float16*)(smem + buf * 16384);
        unsigned long long* lB = (unsigned long long*)(smem + 32768 + buf * 1024);
        #pragma unroll
        for (int i = 0; i < 4; i++){
            int idx = t + 256 * i;
            int dd = idx >> 3, kb = idx & 7;
            *(uint4*)&lD[dd * 64 + ((kb ^ (dd & 7)) * 8)] = rd[i];
        }
        if (t < 128) lB[t] = rb;
    };
    auto compute = [&](int buf){
        const _Float16* lD = (const _Float16*)(smem + buf * 16384);
        const uint2* lB = (const uint2*)(smem + 32768 + buf * 1024);
        uint2 bw0 = lB[w * 32 + fr];
        uint2 bw1 = lB[w * 32 + 16 + fr];
        #pragma unroll
        for (int h = 0; h < 2; h++){
            unsigned word0 = h ? bw0.y : bw0.x;
            unsigned word1 = h ? bw1.y : bw1.x;
            unsigned byte0 = (word0 >> q8) & 0xFFu;
            unsigned byte1 = (word1 >> q8) & 0xFFu;
            f16x8 af0, af1;
            #pragma unroll
            for (int j = 0; j < 8; j++){
                af0[j] = ((byte0 >> j) & 1u) ? (_Float16)1.0f : (_Float16)0.0f;
                af1[j] = ((byte1 >> j) & 1u) ? (_Float16)1.0f : (_Float16)0.0f;
            }
            #pragma unroll
            for (int c = 0; c < 8; c++){
                int drow = c * 16 + fr;
                f16x8 bf = *(const f16x8*)&lD[drow * 64 + (((h * 4 + q) ^ (drow & 7)) * 8)];
                acc[0][c] = __builtin_amdgcn_mfma_f32_16x16x32_f16(af0, bf, acc[0][c], 0, 0, 0);
                acc[1][c] = __builtin_amdgcn_mfma_f32_16x16x32_f16(af1, bf, acc[1][c], 0, 0, 0);
            }
        }
    };

    loadg(0); stage(0); __syncthreads();
    for (int c = 0; c < 32; c++){
        if (c + 1 < 32) loadg((c + 1) * 64);
        compute(c & 1);
        if (c + 1 < 32) stage((c + 1) & 1);
        __syncthreads();
    }

    // Phase 2: Q (f16, per-wave-private rows) @ Wc^T via MFMA.
    _Float16* sQ = (_Float16*)smem;
    #pragma unroll
    for (int u = 0; u < 2; u++)
        #pragma unroll
        for (int c = 0; c < 8; c++)
            #pragma unroll
            for (int reg = 0; reg < 4; reg++){
                int row = w * 32 + u * 16 + q * 4 + reg;
                int col = c * 16 + fr;
                sQ[row * 128 + (((col >> 3) ^ (row & 7)) * 8) + (col & 7)] = (_Float16)acc[u][c][reg];
            }
    f32x4 acc2[2][8] = {};
    #pragma unroll
    for (int kk = 0; kk < 4; kk++){
        int arow0 = w * 32 + fr;
        int arow1 = w * 32 + 16 + fr;
        f16x8 a20 = *(const f16x8*)&sQ[arow0 * 128 + (((kk * 4 + q) ^ (arow0 & 7)) * 8)];
        f16x8 a21 = *(const f16x8*)&sQ[arow1 * 128 + (((kk * 4 + q) ^ (arow1 & 7)) * 8)];
        #pragma unroll
        for (int c = 0; c < 8; c++){
            int n = c * 16 + fr;
            f16x8 b2 = *(const f16x8*)&lWc[n * 128 + (((kk * 4 + q) ^ (n & 7)) * 8)];
            acc2[0][c] = __builtin_amdgcn_mfma_f32_16x16x32_f16(a20, b2, acc2[0][c], 0, 0, 0);
            acc2[1][c] = __builtin_amdgcn_mfma_f32_16x16x32_f16(a21, b2, acc2[1][c], 0, 0, 0);
        }
    }
    __syncthreads();
    float* sD = (float*)smem;                  // 128 x 132 f32 = 67584 B
    #pragma unroll
    for (int u = 0; u < 2; u++)
        #pragma unroll
        for (int c = 0; c < 8; c++)
            #pragma unroll
            for (int reg = 0; reg < 4; reg++)
                sD[(w * 32 + u * 16 + q * 4 + reg) * 132 + c * 16 + fr] = acc2[u][c][reg];
    __syncthreads();
    #pragma unroll
    for (int i = 0; i < 16; i++){
        int idx = t + 256 * i;
        int lrow = idx >> 5, c4 = idx & 31;
        float4 v = *(const float4*)&sD[lrow * 132 + c4 * 4];
        *(float4*)(op + (size_t)lrow * 128 + c4 * 4) = v;
    }
}

// ---------------------------------------------------------------------------
// Pipeline (5 launches; layer recursion = fixed point; ec_Wa dead):
//  1. prep: featT = T(feat) f16 ; Wc16 = f16(eWp@vWp)
//  2. fused_gemm1: ONE inc pass -> p0..p3 (split-K agg) + bitsX
//  3. rowmm_sum4_sm: agg = sum p ; eatt = agg@vWa^T ; softmax partials
//  4. apply_edge_pt: P = agg*softmax(eatt) ; edge = P@vWp^T ; PT = f16(P^T)
//  5. bitgemm2_fused: node = (inc@P)@Wc^T
// ws: [0,8M)=bitsX; [8,40M)=p0..p3 (agg over p0, PT over p1);
//     [40M)=Wc16; [41M)=part (256 KB).
// d_out: node[0,8M)=featT scratch; node[8,16M)=eatt scratch.
// ---------------------------------------------------------------------------
extern "C" void kernel_launch(void* const* d_in, const int* in_sizes, int n_in,
                              void* d_out, int out_size, void* d_ws, size_t ws_size,
                              hipStream_t stream)
{
    const float* feat = (const float*)d_in[0];
    const float* inc  = (const float*)d_in[1];
    const float* vWa  = (const float*)d_in[2];
    const float* vWp  = (const float*)d_in[3];
    const float* eWp  = (const float*)d_in[6];

    float* node_out = (float*)d_out;
    float* edge_out = node_out + (size_t)BB * MM * DD;

    char* w = (char*)d_ws;
    unsigned long long* bitsX = (unsigned long long*)w;        // [0,8M)
    float* pk  = (float*)(w + ((size_t)8 << 20));              // p0..p3 (8 MB each)
    float* agg = pk;                                           // over p0
    _Float16* PT = (_Float16*)(w + ((size_t)16 << 20));        // over p1 (dead after sum4)
    _Float16* Wc16 = (_Float16*)(w + ((size_t)40 << 20));
    float* part = (float*)(w + ((size_t)41 << 20));            // 256 KB

    _Float16* featT = (_Float16*)node_out;                     // node[0,8M)
    float* eattP = node_out + 2097152;                         // node[8,16M)

    dim3 blk(256);

    prep<<<dim3(1088), blk, 0, stream>>>(feat, featT, eWp, vWp, Wc16);
    fused_gemm1<<<dim3(256), blk, 0, stream>>>(inc, featT, bitsX, pk);
    rowmm_sum4_sm<<<dim3(BB * EE / 64), blk, 0, stream>>>(pk, vWa, agg, eattP, part);
    apply_edge_pt<<<dim3(256), blk, 0, stream>>>(eattP, agg, part, vWp, edge_out, PT);
    bitgemm2_fused<<<dim3(256), blk, 0, stream>>>(bitsX, PT, Wc16, node_out);
}